// Round 1
// baseline (135.752 us; speedup 1.0000x reference)
//
#include <hip/hip_runtime.h>
#include <stdint.h>

#define ALPHA_C 1000.0f
#define EPS_C 1e-6f
#define NPTS 8192
#define BATCH 4
#define QPT 8                               // queries per thread
#define TPB 256                             // threads per block
#define SLICES 32
#define CAND_PER_SLICE (NPTS / SLICES)      // 256
#define QCHUNK (TPB * QPT)                  // 2048
#define NQCHUNKS (NPTS / QCHUNK)            // 4
#define TOTQ (2 * BATCH * NPTS)             // 65536 query slots (both dirs)

// ---------------------------------------------------------------------------
// Kernel A: brute-force NN argmax of s = x·y - 0.5*yy + 2  (<=> argmin dist).
// Packed 64-bit key (s_bits<<32 | ~idx) merged across candidate slices with
// atomicMax. ~idx => ties prefer smaller index (matches jnp.argmin).
// ---------------------------------------------------------------------------
__global__ __launch_bounds__(TPB) void nn_kernel(
    const float* __restrict__ x, const float* __restrict__ y,
    unsigned long long* __restrict__ best) {
  int bid = blockIdx.x;
  int slice = bid & (SLICES - 1);
  int qc = (bid >> 5) & (NQCHUNKS - 1);
  int b = (bid >> 7) & (BATCH - 1);
  int dir = bid >> 9;

  const float* qp = (dir == 0 ? x : y) + b * NPTS * 3;
  const float* cp = (dir == 0 ? y : x) + b * NPTS * 3;
  unsigned long long* bq = best + (dir * BATCH + b) * NPTS;

  __shared__ float4 tile[CAND_PER_SLICE];
  int tid = threadIdx.x;
  {
    int c = slice * CAND_PER_SLICE + tid;
    float cx = cp[c * 3 + 0], cy = cp[c * 3 + 1], cz = cp[c * 3 + 2];
    float ct = 2.0f - 0.5f * (cx * cx + cy * cy + cz * cz);
    tile[tid] = make_float4(cx, cy, cz, ct);
  }
  __syncthreads();

  float ax[QPT], ay[QPT], az[QPT], sb[QPT];
  int ib[QPT];
  int qbase = qc * QCHUNK + tid;
#pragma unroll
  for (int j = 0; j < QPT; j++) {
    int q = qbase + j * TPB;
    ax[j] = qp[q * 3 + 0];
    ay[j] = qp[q * 3 + 1];
    az[j] = qp[q * 3 + 2];
    sb[j] = -1.0f;
    ib[j] = 0;
  }

#pragma unroll 4
  for (int m = 0; m < CAND_PER_SLICE; m++) {
    float4 c = tile[m];
#pragma unroll
    for (int j = 0; j < QPT; j++) {
      float t = fmaf(ax[j], c.x, c.w);
      t = fmaf(ay[j], c.y, t);
      t = fmaf(az[j], c.z, t);
      if (t > sb[j]) { sb[j] = t; ib[j] = m; }   // cmp + max + cndmask
    }
  }

  int cbase = slice * CAND_PER_SLICE;
#pragma unroll
  for (int j = 0; j < QPT; j++) {
    unsigned int sbits = __float_as_uint(sb[j]);
    unsigned long long key =
        ((unsigned long long)sbits << 32) |
        (unsigned long long)(unsigned int)(~(cbase + ib[j]));
    atomicMax(bq + qbase + j * TPB, key);
  }
}

// ---------------------------------------------------------------------------
// Kernel B: histogram of NN indices per (dir, batch).
// ---------------------------------------------------------------------------
__global__ __launch_bounds__(TPB) void count_kernel(
    const unsigned long long* __restrict__ best,
    unsigned int* __restrict__ counts) {
  int i = blockIdx.x * blockDim.x + threadIdx.x;  // 0..TOTQ-1
  unsigned int idx = ~(unsigned int)(best[i] & 0xFFFFFFFFull);
  int db = i >> 13;  // (dir*4 + b)
  atomicAdd(counts + (db << 13) + idx, 1u);
}

// ---------------------------------------------------------------------------
// Kernel C: per-query loss term exp(-alpha*d)/(cnt+eps), exact d recomputed
// for the winner in the reference's fp ordering; reduce into accum.
// ---------------------------------------------------------------------------
__global__ __launch_bounds__(TPB) void loss_kernel(
    const float* __restrict__ x, const float* __restrict__ y,
    const unsigned long long* __restrict__ best,
    const unsigned int* __restrict__ counts,
    float* __restrict__ accum) {
  int i = blockIdx.x * blockDim.x + threadIdx.x;
  int q = i & (NPTS - 1);
  int db = i >> 13;
  int b = db & (BATCH - 1);
  int dir = db >> 2;
  const float* qp = (dir == 0 ? x : y) + b * NPTS * 3;
  const float* cp = (dir == 0 ? y : x) + b * NPTS * 3;

  unsigned long long key = best[i];
  unsigned int idx = ~(unsigned int)(key & 0xFFFFFFFFull);

  float axv = qp[q * 3 + 0], ayv = qp[q * 3 + 1], azv = qp[q * 3 + 2];
  float bxv = cp[idx * 3 + 0], byv = cp[idx * 3 + 1], bzv = cp[idx * 3 + 2];
  float xx = axv * axv + ayv * ayv + azv * azv;
  float yy = bxv * bxv + byv * byv + bzv * bzv;
  float xy = axv * bxv + ayv * byv + azv * bzv;
  float d = xx - 2.0f * xy + yy;

  float cnt = (float)counts[(db << 13) + idx];
  float w = 1.0f / (cnt + EPS_C);
  float v = expf(-d * ALPHA_C) * w;

  // wave-64 reduction, then one atomic per wave
#pragma unroll
  for (int o = 32; o > 0; o >>= 1) v += __shfl_down(v, o);
  if ((threadIdx.x & 63) == 0) atomicAdd(accum, v);
}

// ---------------------------------------------------------------------------
// Kernel D: out = mean_b((loss1+loss2)/2) = 1 - sum/65536
// ---------------------------------------------------------------------------
__global__ void finalize_kernel(const float* __restrict__ accum,
                                float* __restrict__ out) {
  out[0] = 1.0f - accum[0] * (1.0f / (float)TOTQ);
}

extern "C" void kernel_launch(void* const* d_in, const int* in_sizes, int n_in,
                              void* d_out, int out_size, void* d_ws,
                              size_t ws_size, hipStream_t stream) {
  const float* x = (const float*)d_in[0];
  const float* y = (const float*)d_in[1];
  float* out = (float*)d_out;

  // ws layout: [best keys: TOTQ*8][counts: TOTQ*4][accum: 4]
  unsigned long long* best = (unsigned long long*)d_ws;
  unsigned int* counts = (unsigned int*)((char*)d_ws + (size_t)TOTQ * 8);
  float* accum = (float*)((char*)d_ws + (size_t)TOTQ * 8 + (size_t)TOTQ * 4);

  hipMemsetAsync(d_ws, 0, (size_t)TOTQ * 12 + 16, stream);

  int nblocks = 2 * BATCH * NQCHUNKS * SLICES;  // 1024
  nn_kernel<<<nblocks, TPB, 0, stream>>>(x, y, best);
  count_kernel<<<TOTQ / TPB, TPB, 0, stream>>>(best, counts);
  loss_kernel<<<TOTQ / TPB, TPB, 0, stream>>>(x, y, best, counts, accum);
  finalize_kernel<<<1, 1, 0, stream>>>(accum, out);
}